// Round 14
// baseline (717.192 us; speedup 1.0000x reference)
//
#include <hip/hip_runtime.h>
#include <math.h>

static constexpr int NN   = 100000;   // nodes
static constexpr int NE   = 3200000;  // edges (before self loops)
static constexpr int ET   = NE + NN;  // edges incl self loops
static constexpr int DIN  = 128;
static constexpr int H1   = 8;        // heads layer 1
static constexpr int C1   = 32;       // H1*F1
static constexpr int DOUT = 64;
static constexpr int NG   = 64;       // graphs
static constexpr int NB_SCAN = (NN + 255) / 256;   // 391
static constexpr int SLAB = (NN + 255) / 256;      // nodes per pool block
static constexpr int NODES_PER_XCD = (NN + 7) / 8; // 12500
static constexpr int SC_SLABS = (ET + 255) / 256;  // scatter slabs

using fx4 = __attribute__((ext_vector_type(4))) float;   // NT-store-compatible float4

__device__ __forceinline__ float lrelu(float x){ return x > 0.f ? x : 0.2f*x; }
__device__ __forceinline__ float bfl(unsigned int u){ return __uint_as_float(u << 16); }
__device__ __forceinline__ float bfh(unsigned int u){ return __uint_as_float(u & 0xffff0000u); }
// fp32 -> bf16 (RNE) stored as ushort
__device__ __forceinline__ unsigned short f2bf(float x){
  unsigned int u = __float_as_uint(x);
  u += 0x7fffu + ((u >> 16) & 1u);
  return (unsigned short)(u >> 16);
}

// ---------- GEMM1 (x@W1) fused with att1 dots; h1 stored bf16 ----------
__global__ __launch_bounds__(256) void k_gemm1(const float* __restrict__ x,
                                               const float* __restrict__ W,
                                               const float* __restrict__ as1,
                                               const float* __restrict__ ad1,
                                               unsigned short* __restrict__ h1b,
                                               float* __restrict__ a_s,
                                               float* __restrict__ a_d){
  __shared__ float w[DIN * C1];
  for (int i = threadIdx.x; i < DIN * C1; i += 256) w[i] = W[i];
  __syncthreads();
  int idx = blockIdx.x * 256 + threadIdx.x;
  int n = idx >> 5, j = idx & 31;           // j = h*4+f
  const float* xr = x + (size_t)n * DIN;
  float acc = 0.f;
  #pragma unroll
  for (int k = 0; k < DIN; ++k) acc += __builtin_nontemporal_load(xr + k) * w[k * C1 + j];
  h1b[idx] = f2bf(acc);
  float s = acc * as1[j], d = acc * ad1[j];
  s += __shfl_xor(s, 1, 64); s += __shfl_xor(s, 2, 64);
  d += __shfl_xor(d, 1, 64); d += __shfl_xor(d, 2, 64);
  if ((j & 3) == 0){ a_s[n * H1 + (j >> 2)] = s; a_d[n * H1 + (j >> 2)] = d; }
}

// ---------- counting sort of edges by dst (XCD-partitioned hist + scatter) ----------
// 8 blocks per edge-slab; block handles only dsts owned by its XCD (blockIdx&7)
__global__ __launch_bounds__(256) void k_hist8(const int* __restrict__ ei, int* __restrict__ cnt){
  int xcd = blockIdx.x & 7;
  int e = (blockIdx.x >> 3) * 256 + threadIdx.x;   // e < NE (grid exact)
  int d = __builtin_nontemporal_load(ei + NE + e);
  if (d / NODES_PER_XCD == xcd) atomicAdd(&cnt[d], 1);
}

// scans add +1 per node for the self-loop (cnt holds only real-edge counts)
__global__ __launch_bounds__(256) void k_scan_blk(const int* __restrict__ cnt,
                                                  int* __restrict__ tmp, int* __restrict__ btot){
  int g = blockIdx.x * 256 + threadIdx.x;
  int v = (g < NN) ? cnt[g] + 1 : 0;
  int lane = threadIdx.x & 63, wv = threadIdx.x >> 6;
  int xv = v;
  #pragma unroll
  for (int o = 1; o < 64; o <<= 1){ int y = __shfl_up(xv, o, 64); if (lane >= o) xv += y; }
  __shared__ int ws[4];
  if (lane == 63) ws[wv] = xv;
  __syncthreads();
  int off = 0;
  for (int i = 0; i < wv; ++i) off += ws[i];
  xv += off;
  if (g < NN) tmp[g] = xv;                        // inclusive within block
  if (threadIdx.x == 255) btot[blockIdx.x] = xv;  // block total
}

__global__ __launch_bounds__(512) void k_scan_top(int* __restrict__ btot){
  int t = threadIdx.x;
  int v = (t < NB_SCAN) ? btot[t] : 0;
  int lane = t & 63, wv = t >> 6;
  int xv = v;
  #pragma unroll
  for (int o = 1; o < 64; o <<= 1){ int y = __shfl_up(xv, o, 64); if (lane >= o) xv += y; }
  __shared__ int ws[8];
  if (lane == 63) ws[wv] = xv;
  __syncthreads();
  int off = 0;
  for (int i = 0; i < wv; ++i) off += ws[i];
  xv += off;
  if (t < NB_SCAN) btot[t] = xv - v;              // exclusive block prefix
}

__global__ __launch_bounds__(256) void k_scan_fin(const int* __restrict__ cnt,
                                                  const int* __restrict__ tmp,
                                                  const int* __restrict__ btot,
                                                  int* __restrict__ row, int* __restrict__ cur){
  int g = blockIdx.x * 256 + threadIdx.x;
  if (g < NN){
    int ex = tmp[g] - (cnt[g] + 1) + btot[g >> 8];
    row[g] = ex; cur[g] = ex;
  } else if (g == NN){
    row[NN] = ET;
  }
}

// 8 blocks per edge-slab; each XCD writes only its own contiguous ssrc range
__global__ __launch_bounds__(256) void k_scatter8(const int* __restrict__ ei,
                                                  int* __restrict__ cur, int* __restrict__ ssrc){
  int xcd = blockIdx.x & 7;
  int e = (blockIdx.x >> 3) * 256 + threadIdx.x;
  if (e >= ET) return;
  int s, d;
  if (e < NE) { d = __builtin_nontemporal_load(ei + NE + e); s = -1; }
  else        { s = e - NE; d = s; }
  if (d / NODES_PER_XCD != xcd) return;
  if (s < 0) s = __builtin_nontemporal_load(ei + e);
  int pos = atomicAdd(&cur[d], 1);
  ssrc[pos] = s;                                   // NOT non-temporal: must coalesce in L2
}

// ---------- layer-1 aggregation: wave/node, 8 lanes/edge, two-level pipelined loads ----------
// lane = g*8 + l : group g (0..7) handles edge slot, lane-l owns head l (feats 4l..4l+3)
__global__ __launch_bounds__(256, 4) void k_agg1(const int* __restrict__ row,
                                              const int* __restrict__ ssrc,
                                              const float* __restrict__ a_s,
                                              const float* __restrict__ a_d,
                                              const unsigned short* __restrict__ h1b,
                                              const float* __restrict__ b1,
                                              float* __restrict__ out1){
  int node = (blockIdx.x * 256 + threadIdx.x) >> 6;
  int lane = threadIdx.x & 63;
  int l = lane & 7, g = lane >> 3;
  float adv = a_d[node * H1 + l];
  int beg = row[node], end = row[node + 1];
  float a0 = 0.f, a1 = 0.f, a2 = 0.f, a3 = 0.f, den = 0.f;
  for (int base = beg; base < end; base += 64){
    int sv[8]; float liv[8];
    #pragma unroll
    for (int u = 0; u < 8; ++u){               // level 1: edge srcs (broadcast in group)
      int k = base + u * 8 + g;
      liv[u] = (k < end) ? 1.f : 0.f;
      sv[u] = __builtin_nontemporal_load(ssrc + (k < end ? k : end - 1));
    }
    uint2 hraw[8]; float araw[8];
    #pragma unroll
    for (int u = 0; u < 8; ++u){               // level 2: dependent gathers
      hraw[u] = *(const uint2*)(h1b + (size_t)sv[u] * C1 + 4 * l);
      araw[u] = a_s[sv[u] * H1 + l];
    }
    #pragma unroll
    for (int u = 0; u < 8; ++u){               // level 3: math
      float al = liv[u] * __expf(lrelu(araw[u] + adv));
      den += al;
      a0 += al * bfl(hraw[u].x); a1 += al * bfh(hraw[u].x);
      a2 += al * bfl(hraw[u].y); a3 += al * bfh(hraw[u].y);
    }
  }
  #pragma unroll
  for (int o = 8; o < 64; o <<= 1){
    den += __shfl_xor(den, o, 64);
    a0 += __shfl_xor(a0, o, 64); a1 += __shfl_xor(a1, o, 64);
    a2 += __shfl_xor(a2, o, 64); a3 += __shfl_xor(a3, o, 64);
  }
  if (g == 0){
    float r = 1.f / den;
    float4 bv = *(const float4*)(b1 + 4 * l);
    float v0 = a0 * r + bv.x, v1 = a1 * r + bv.y, v2 = a2 * r + bv.z, v3 = a3 * r + bv.w;
    v0 = v0 > 0.f ? v0 : expm1f(v0); v1 = v1 > 0.f ? v1 : expm1f(v1);
    v2 = v2 > 0.f ? v2 : expm1f(v2); v3 = v3 > 0.f ? v3 : expm1f(v3);
    fx4 o4; o4.x = v0; o4.y = v1; o4.z = v2; o4.w = v3;
    __builtin_nontemporal_store(o4, (fx4*)(out1 + (size_t)node * C1 + 4 * l));
  }
}

// ---------- GEMM2 (out1@W2) fused with att2 dots; h2 stored bf16 ----------
__global__ __launch_bounds__(256) void k_gemm2(const float* __restrict__ hin,
                                               const float* __restrict__ W,
                                               const float* __restrict__ as2,
                                               const float* __restrict__ ad2,
                                               unsigned short* __restrict__ h2b,
                                               float* __restrict__ a_s,
                                               float* __restrict__ a_d){
  __shared__ float w[C1 * DOUT];
  for (int i = threadIdx.x; i < C1 * DOUT; i += 256) w[i] = W[i];
  __syncthreads();
  int idx = blockIdx.x * 256 + threadIdx.x;
  int n = idx >> 6, j = idx & 63;
  const float* hr = hin + (size_t)n * C1;
  float acc = 0.f;
  #pragma unroll
  for (int k = 0; k < C1; ++k) acc += hr[k] * w[k * DOUT + j];
  h2b[idx] = f2bf(acc);
  float s = acc * as2[j], d = acc * ad2[j];
  #pragma unroll
  for (int o = 1; o < 64; o <<= 1){ s += __shfl_xor(s, o, 64); d += __shfl_xor(d, o, 64); }
  if (j == 0){ a_s[n] = s; a_d[n] = d; }
}

// ---------- layer-2 aggregation: wave/node, 16 lanes/edge, NO atomics (plain out2) ----------
// lane = g*16 + l : group g (0..3) handles edge slot, lane-l owns feats 4l..4l+3
__global__ __launch_bounds__(256, 4) void k_agg2(const int* __restrict__ row,
                                              const int* __restrict__ ssrc,
                                              const float* __restrict__ a_s,
                                              const float* __restrict__ a_d,
                                              const unsigned short* __restrict__ h2b,
                                              float* __restrict__ out2){
  int node = (blockIdx.x * 256 + threadIdx.x) >> 6;
  int lane = threadIdx.x & 63;
  int l = lane & 15, g = lane >> 4;
  float adv = a_d[node];
  int beg = row[node], end = row[node + 1];
  float ac0 = 0.f, ac1 = 0.f, ac2 = 0.f, ac3 = 0.f, den = 0.f;
  for (int base = beg; base < end; base += 32){
    int sv[8]; float liv[8];
    #pragma unroll
    for (int u = 0; u < 8; ++u){               // level 1: edge srcs (broadcast in group)
      int k = base + u * 4 + g;
      liv[u] = (k < end) ? 1.f : 0.f;
      sv[u] = __builtin_nontemporal_load(ssrc + (k < end ? k : end - 1));
    }
    uint2 hraw[8]; float asv[8];
    #pragma unroll
    for (int u = 0; u < 8; ++u){               // level 2: dependent gathers
      hraw[u] = *(const uint2*)(h2b + (size_t)sv[u] * DOUT + 4 * l);
      asv[u] = a_s[sv[u]];
    }
    #pragma unroll
    for (int u = 0; u < 8; ++u){               // level 3: math
      float al = liv[u] * __expf(lrelu(asv[u] + adv));
      den += al;
      ac0 += al * bfl(hraw[u].x); ac1 += al * bfh(hraw[u].x);
      ac2 += al * bfl(hraw[u].y); ac3 += al * bfh(hraw[u].y);
    }
  }
  #pragma unroll
  for (int o = 16; o < 64; o <<= 1){
    den += __shfl_xor(den, o, 64);
    ac0 += __shfl_xor(ac0, o, 64); ac1 += __shfl_xor(ac1, o, 64);
    ac2 += __shfl_xor(ac2, o, 64); ac3 += __shfl_xor(ac3, o, 64);
  }
  if (g == 0){
    float r = 1.f / den;
    fx4 o4; o4.x = ac0 * r; o4.y = ac1 * r; o4.z = ac2 * r; o4.w = ac3 * r;
    __builtin_nontemporal_store(o4, (fx4*)(out2 + (size_t)node * DOUT + 4 * l));
  }
}

// ---------- graph boundaries from sorted batch (no atomics) ----------
__global__ __launch_bounds__(256) void k_bounds(const int* __restrict__ batch,
                                                int* __restrict__ gs){
  int n = blockIdx.x * 256 + threadIdx.x;
  if (n >= NN) return;
  int b = batch[n];
  if (n == 0) gs[b] = 0;
  else if (batch[n - 1] != b) gs[b] = n;
}

__global__ void k_fix(int* __restrict__ gs){
  if (threadIdx.x == 0){
    gs[NG] = NN;
    for (int g = NG - 1; g >= 0; --g) if (gs[g] < 0) gs[g] = gs[g + 1];
  }
}

// ---------- pool: 256 blocks, per-wave local accumulation, flush on graph change ----------
__global__ __launch_bounds__(256) void k_pool(const float* __restrict__ out2,
                                              const int* __restrict__ batch,
                                              float* __restrict__ sums){
  int start = blockIdx.x * SLAB;
  int stop  = start + SLAB; if (stop > NN) stop = NN;
  int wv = threadIdx.x >> 6, lane = threadIdx.x & 63;
  int n0 = start + wv;
  if (n0 >= stop) return;
  float acc = 0.f;
  int cur_g = batch[n0];
  for (int n = n0; n < stop; n += 4){
    int g = batch[n];
    if (g != cur_g){
      atomicAdd(&sums[cur_g * DOUT + lane], acc);
      acc = 0.f; cur_g = g;
    }
    acc += __builtin_nontemporal_load(out2 + (size_t)n * DOUT + lane);
  }
  atomicAdd(&sums[cur_g * DOUT + lane], acc);
}

__global__ __launch_bounds__(256) void k_final(const float* __restrict__ sums,
                                               const int* __restrict__ gs,
                                               const float* __restrict__ b2,
                                               float* __restrict__ out){
  int idx = blockIdx.x * 256 + threadIdx.x;
  if (idx >= NG * DOUT) return;
  int g = idx >> 6, f = idx & 63;
  int c = gs[g + 1] - gs[g];
  out[idx] = sums[idx] / (float)(c > 0 ? c : 1) + b2[f];
}

extern "C" void kernel_launch(void* const* d_in, const int* in_sizes, int n_in,
                              void* d_out, int out_size, void* d_ws, size_t ws_size,
                              hipStream_t stream) {
  const float* x   = (const float*)d_in[0];
  const int*   ei  = (const int*)  d_in[1];
  const int*   bat = (const int*)  d_in[2];
  const float* W1  = (const float*)d_in[3];
  const float* as1 = (const float*)d_in[4];
  const float* ad1 = (const float*)d_in[5];
  const float* b1  = (const float*)d_in[6];
  const float* W2  = (const float*)d_in[7];
  const float* as2 = (const float*)d_in[8];
  const float* ad2 = (const float*)d_in[9];
  const float* b2  = (const float*)d_in[10];
  float* out = (float*)d_out;

  char* p = (char*)d_ws;
  auto alloc = [&](size_t bytes){ void* r = p; p += (bytes + 255) & ~(size_t)255; return r; };
  unsigned short* h1b  = (unsigned short*)alloc((size_t)NN * C1 * 2);
  float* a_s1  = (float*)alloc((size_t)NN * H1 * 4);
  float* a_d1  = (float*)alloc((size_t)NN * H1 * 4);
  float* out1  = (float*)alloc((size_t)NN * C1 * 4);
  unsigned short* h2b  = (unsigned short*)alloc((size_t)NN * DOUT * 2);
  float* a_s2  = (float*)alloc(NN * 4);
  float* a_d2  = (float*)alloc(NN * 4);
  float* out2  = (float*)alloc((size_t)NN * DOUT * 4);
  int*   row   = (int*)alloc((NN + 1) * 4);
  int*   cur   = (int*)alloc(NN * 4);
  int*   tmp   = (int*)alloc(NN * 4);
  int*   btot  = (int*)alloc(512 * 4);
  int*   cnt   = (int*)alloc(NN * 4);
  int*   ssrc  = (int*)alloc((size_t)ET * 4);
  float* sums  = (float*)alloc(NG * DOUT * 4);
  int*   gs    = (int*)alloc((NG + 1) * 4);

  hipMemsetAsync(sums, 0, NG * DOUT * 4, stream);
  hipMemsetAsync(gs, 0xFF, (NG + 1) * 4, stream);
  hipMemsetAsync(cnt, 0, NN * 4, stream);

  // node transform 1
  k_gemm1<<<(NN * C1) / 256, 256, 0, stream>>>(x, W1, as1, ad1, h1b, a_s1, a_d1);

  // counting sort by dst (XCD-partitioned hist & scatter)
  k_hist8   <<<(NE / 256) * 8, 256, 0, stream>>>(ei, cnt);
  k_scan_blk<<<NB_SCAN, 256, 0, stream>>>(cnt, tmp, btot);
  k_scan_top<<<1, 512, 0, stream>>>(btot);
  k_scan_fin<<<(NN + 256) / 256, 256, 0, stream>>>(cnt, tmp, btot, row, cur);
  k_scatter8<<<SC_SLABS * 8, 256, 0, stream>>>(ei, cur, ssrc);

  // graph boundaries (for pool counts)
  k_bounds<<<(NN + 255) / 256, 256, 0, stream>>>(bat, gs);
  k_fix<<<1, 64, 0, stream>>>(gs);

  // layer 1 aggregate (+bias+ELU)
  k_agg1<<<(NN * 64) / 256, 256, 0, stream>>>(row, ssrc, a_s1, a_d1, h1b, b1, out1);

  // layer 2
  k_gemm2<<<(NN * DOUT) / 256, 256, 0, stream>>>(out1, W2, as2, ad2, h2b, a_s2, a_d2);
  k_agg2 <<<(NN * 64) / 256, 256, 0, stream>>>(row, ssrc, a_s2, a_d2, h2b, out2);

  // pool + finalize
  k_pool <<<256, 256, 0, stream>>>(out2, bat, sums);
  k_final<<<(NG * DOUT + 255) / 256, 256, 0, stream>>>(sums, gs, b2, out);
}

// Round 16
// 671.336 us; speedup vs baseline: 1.0683x; 1.0683x over previous
//
#include <hip/hip_runtime.h>
#include <math.h>

static constexpr int NN   = 100000;   // nodes
static constexpr int NE   = 3200000;  // edges (before self loops)
static constexpr int ET   = NE + NN;  // edges incl self loops
static constexpr int DIN  = 128;
static constexpr int H1   = 8;        // heads layer 1
static constexpr int C1   = 32;       // H1*F1
static constexpr int DOUT = 64;
static constexpr int NG   = 64;       // graphs
static constexpr int NB_SCAN = (NN + 255) / 256;   // 391
static constexpr int SLAB = (NN + 255) / 256;      // nodes per pool block
static constexpr int NODES_PER_XCD = (NN + 7) / 8; // 12500
static constexpr int SC_SLABS = (ET + 255) / 256;  // scatter slabs

__device__ __forceinline__ float lrelu(float x){ return x > 0.f ? x : 0.2f*x; }
__device__ __forceinline__ float bfl(unsigned int u){ return __uint_as_float(u << 16); }
__device__ __forceinline__ float bfh(unsigned int u){ return __uint_as_float(u & 0xffff0000u); }
// fp32 -> bf16 (RNE) stored as ushort
__device__ __forceinline__ unsigned short f2bf(float x){
  unsigned int u = __float_as_uint(x);
  u += 0x7fffu + ((u >> 16) & 1u);
  return (unsigned short)(u >> 16);
}

// ---------- GEMM1 (x@W1) fused with att1 dots; h1 stored bf16 ----------
__global__ __launch_bounds__(256) void k_gemm1(const float* __restrict__ x,
                                               const float* __restrict__ W,
                                               const float* __restrict__ as1,
                                               const float* __restrict__ ad1,
                                               unsigned short* __restrict__ h1b,
                                               float* __restrict__ a_s,
                                               float* __restrict__ a_d){
  __shared__ float w[DIN * C1];
  for (int i = threadIdx.x; i < DIN * C1; i += 256) w[i] = W[i];
  __syncthreads();
  int idx = blockIdx.x * 256 + threadIdx.x;
  int n = idx >> 5, j = idx & 31;           // j = h*4+f
  const float* xr = x + (size_t)n * DIN;
  float acc = 0.f;
  #pragma unroll
  for (int k = 0; k < DIN; ++k) acc += xr[k] * w[k * C1 + j];
  h1b[idx] = f2bf(acc);
  float s = acc * as1[j], d = acc * ad1[j];
  s += __shfl_xor(s, 1, 64); s += __shfl_xor(s, 2, 64);
  d += __shfl_xor(d, 1, 64); d += __shfl_xor(d, 2, 64);
  if ((j & 3) == 0){ a_s[n * H1 + (j >> 2)] = s; a_d[n * H1 + (j >> 2)] = d; }
}

// ---------- counting sort of edges by dst ----------
// simple single-read hist; cross-XCD atomics on 400KB cnt are cheap (R8-measured)
__global__ __launch_bounds__(256) void k_hist(const int* __restrict__ ei, int* __restrict__ cnt){
  int e = blockIdx.x * 256 + threadIdx.x;   // e < NE exactly (grid divisible)
  int d = __builtin_nontemporal_load(ei + NE + e);
  atomicAdd(&cnt[d], 1);
}

// scans add +1 per node for the self-loop (cnt holds only real-edge counts)
__global__ __launch_bounds__(256) void k_scan_blk(const int* __restrict__ cnt,
                                                  int* __restrict__ tmp, int* __restrict__ btot){
  int g = blockIdx.x * 256 + threadIdx.x;
  int v = (g < NN) ? cnt[g] + 1 : 0;
  int lane = threadIdx.x & 63, wv = threadIdx.x >> 6;
  int xv = v;
  #pragma unroll
  for (int o = 1; o < 64; o <<= 1){ int y = __shfl_up(xv, o, 64); if (lane >= o) xv += y; }
  __shared__ int ws[4];
  if (lane == 63) ws[wv] = xv;
  __syncthreads();
  int off = 0;
  for (int i = 0; i < wv; ++i) off += ws[i];
  xv += off;
  if (g < NN) tmp[g] = xv;                        // inclusive within block
  if (threadIdx.x == 255) btot[blockIdx.x] = xv;  // block total
}

__global__ __launch_bounds__(512) void k_scan_top(int* __restrict__ btot){
  int t = threadIdx.x;
  int v = (t < NB_SCAN) ? btot[t] : 0;
  int lane = t & 63, wv = t >> 6;
  int xv = v;
  #pragma unroll
  for (int o = 1; o < 64; o <<= 1){ int y = __shfl_up(xv, o, 64); if (lane >= o) xv += y; }
  __shared__ int ws[8];
  if (lane == 63) ws[wv] = xv;
  __syncthreads();
  int off = 0;
  for (int i = 0; i < wv; ++i) off += ws[i];
  xv += off;
  if (t < NB_SCAN) btot[t] = xv - v;              // exclusive block prefix
}

__global__ __launch_bounds__(256) void k_scan_fin(const int* __restrict__ cnt,
                                                  const int* __restrict__ tmp,
                                                  const int* __restrict__ btot,
                                                  int* __restrict__ row, int* __restrict__ cur){
  int g = blockIdx.x * 256 + threadIdx.x;
  if (g < NN){
    int ex = tmp[g] - (cnt[g] + 1) + btot[g >> 8];
    row[g] = ex; cur[g] = ex;
  } else if (g == NN){
    row[NN] = ET;
  }
}

// 8 blocks per edge-slab; each XCD writes only its own contiguous ssrc range
__global__ __launch_bounds__(256) void k_scatter8(const int* __restrict__ ei,
                                                  int* __restrict__ cur, int* __restrict__ ssrc){
  int xcd = blockIdx.x & 7;
  int e = (blockIdx.x >> 3) * 256 + threadIdx.x;
  if (e >= ET) return;
  int s, d;
  if (e < NE) { d = __builtin_nontemporal_load(ei + NE + e); s = -1; }
  else        { s = e - NE; d = s; }
  if (d / NODES_PER_XCD != xcd) return;
  if (s < 0) s = __builtin_nontemporal_load(ei + e);
  int pos = atomicAdd(&cur[d], 1);
  ssrc[pos] = s;                                   // NOT non-temporal: must coalesce in L2
}

// ---------- layer-1 aggregation: wave/node, 8 lanes/edge, two-level pipelined loads ----------
// lane = g*8 + l : group g (0..7) handles edge slot, lane-l owns head l (feats 4l..4l+3)
__global__ __launch_bounds__(256, 4) void k_agg1(const int* __restrict__ row,
                                              const int* __restrict__ ssrc,
                                              const float* __restrict__ a_s,
                                              const float* __restrict__ a_d,
                                              const unsigned short* __restrict__ h1b,
                                              const float* __restrict__ b1,
                                              float* __restrict__ out1){
  int node = (blockIdx.x * 256 + threadIdx.x) >> 6;
  int lane = threadIdx.x & 63;
  int l = lane & 7, g = lane >> 3;
  float adv = a_d[node * H1 + l];
  int beg = row[node], end = row[node + 1];
  float a0 = 0.f, a1 = 0.f, a2 = 0.f, a3 = 0.f, den = 0.f;
  for (int base = beg; base < end; base += 64){
    int sv[8]; float liv[8];
    #pragma unroll
    for (int u = 0; u < 8; ++u){               // level 1: edge srcs (broadcast in group)
      int k = base + u * 8 + g;
      liv[u] = (k < end) ? 1.f : 0.f;
      sv[u] = ssrc[k < end ? k : end - 1];
    }
    uint2 hraw[8]; float araw[8];
    #pragma unroll
    for (int u = 0; u < 8; ++u){               // level 2: dependent gathers
      hraw[u] = *(const uint2*)(h1b + (size_t)sv[u] * C1 + 4 * l);
      araw[u] = a_s[sv[u] * H1 + l];
    }
    #pragma unroll
    for (int u = 0; u < 8; ++u){               // level 3: math
      float al = liv[u] * __expf(lrelu(araw[u] + adv));
      den += al;
      a0 += al * bfl(hraw[u].x); a1 += al * bfh(hraw[u].x);
      a2 += al * bfl(hraw[u].y); a3 += al * bfh(hraw[u].y);
    }
  }
  #pragma unroll
  for (int o = 8; o < 64; o <<= 1){
    den += __shfl_xor(den, o, 64);
    a0 += __shfl_xor(a0, o, 64); a1 += __shfl_xor(a1, o, 64);
    a2 += __shfl_xor(a2, o, 64); a3 += __shfl_xor(a3, o, 64);
  }
  if (g == 0){
    float r = 1.f / den;
    float4 bv = *(const float4*)(b1 + 4 * l);
    float v0 = a0 * r + bv.x, v1 = a1 * r + bv.y, v2 = a2 * r + bv.z, v3 = a3 * r + bv.w;
    v0 = v0 > 0.f ? v0 : expm1f(v0); v1 = v1 > 0.f ? v1 : expm1f(v1);
    v2 = v2 > 0.f ? v2 : expm1f(v2); v3 = v3 > 0.f ? v3 : expm1f(v3);
    *(float4*)(out1 + (size_t)node * C1 + 4 * l) = make_float4(v0, v1, v2, v3);
  }
}

// ---------- GEMM2 (out1@W2) fused with att2 dots; h2 stored bf16 ----------
__global__ __launch_bounds__(256) void k_gemm2(const float* __restrict__ hin,
                                               const float* __restrict__ W,
                                               const float* __restrict__ as2,
                                               const float* __restrict__ ad2,
                                               unsigned short* __restrict__ h2b,
                                               float* __restrict__ a_s,
                                               float* __restrict__ a_d){
  __shared__ float w[C1 * DOUT];
  for (int i = threadIdx.x; i < C1 * DOUT; i += 256) w[i] = W[i];
  __syncthreads();
  int idx = blockIdx.x * 256 + threadIdx.x;
  int n = idx >> 6, j = idx & 63;
  const float* hr = hin + (size_t)n * C1;
  float acc = 0.f;
  #pragma unroll
  for (int k = 0; k < C1; ++k) acc += hr[k] * w[k * DOUT + j];
  h2b[idx] = f2bf(acc);
  float s = acc * as2[j], d = acc * ad2[j];
  #pragma unroll
  for (int o = 1; o < 64; o <<= 1){ s += __shfl_xor(s, o, 64); d += __shfl_xor(d, o, 64); }
  if (j == 0){ a_s[n] = s; a_d[n] = d; }
}

// ---------- layer-2 aggregation: wave/node, 16 lanes/edge, NO atomics (plain out2) ----------
// lane = g*16 + l : group g (0..3) handles edge slot, lane-l owns feats 4l..4l+3
__global__ __launch_bounds__(256, 4) void k_agg2(const int* __restrict__ row,
                                              const int* __restrict__ ssrc,
                                              const float* __restrict__ a_s,
                                              const float* __restrict__ a_d,
                                              const unsigned short* __restrict__ h2b,
                                              float* __restrict__ out2){
  int node = (blockIdx.x * 256 + threadIdx.x) >> 6;
  int lane = threadIdx.x & 63;
  int l = lane & 15, g = lane >> 4;
  float adv = a_d[node];
  int beg = row[node], end = row[node + 1];
  float ac0 = 0.f, ac1 = 0.f, ac2 = 0.f, ac3 = 0.f, den = 0.f;
  for (int base = beg; base < end; base += 32){
    int sv[8]; float liv[8];
    #pragma unroll
    for (int u = 0; u < 8; ++u){               // level 1: edge srcs (broadcast in group)
      int k = base + u * 4 + g;
      liv[u] = (k < end) ? 1.f : 0.f;
      sv[u] = ssrc[k < end ? k : end - 1];
    }
    uint2 hraw[8]; float asv[8];
    #pragma unroll
    for (int u = 0; u < 8; ++u){               // level 2: dependent gathers
      hraw[u] = *(const uint2*)(h2b + (size_t)sv[u] * DOUT + 4 * l);
      asv[u] = a_s[sv[u]];
    }
    #pragma unroll
    for (int u = 0; u < 8; ++u){               // level 3: math
      float al = liv[u] * __expf(lrelu(asv[u] + adv));
      den += al;
      ac0 += al * bfl(hraw[u].x); ac1 += al * bfh(hraw[u].x);
      ac2 += al * bfl(hraw[u].y); ac3 += al * bfh(hraw[u].y);
    }
  }
  #pragma unroll
  for (int o = 16; o < 64; o <<= 1){
    den += __shfl_xor(den, o, 64);
    ac0 += __shfl_xor(ac0, o, 64); ac1 += __shfl_xor(ac1, o, 64);
    ac2 += __shfl_xor(ac2, o, 64); ac3 += __shfl_xor(ac3, o, 64);
  }
  if (g == 0){
    float r = 1.f / den;
    *(float4*)(out2 + (size_t)node * DOUT + 4 * l) =
        make_float4(ac0 * r, ac1 * r, ac2 * r, ac3 * r);
  }
}

// ---------- graph boundaries from sorted batch (no atomics) ----------
__global__ __launch_bounds__(256) void k_bounds(const int* __restrict__ batch,
                                                int* __restrict__ gs){
  int n = blockIdx.x * 256 + threadIdx.x;
  if (n >= NN) return;
  int b = batch[n];
  if (n == 0) gs[b] = 0;
  else if (batch[n - 1] != b) gs[b] = n;
}

__global__ void k_fix(int* __restrict__ gs){
  if (threadIdx.x == 0){
    gs[NG] = NN;
    for (int g = NG - 1; g >= 0; --g) if (gs[g] < 0) gs[g] = gs[g + 1];
  }
}

// ---------- pool: 256 blocks, per-wave local accumulation, flush on graph change ----------
__global__ __launch_bounds__(256) void k_pool(const float* __restrict__ out2,
                                              const int* __restrict__ batch,
                                              float* __restrict__ sums){
  int start = blockIdx.x * SLAB;
  int stop  = start + SLAB; if (stop > NN) stop = NN;
  int wv = threadIdx.x >> 6, lane = threadIdx.x & 63;
  int n0 = start + wv;
  if (n0 >= stop) return;
  float acc = 0.f;
  int cur_g = batch[n0];
  for (int n = n0; n < stop; n += 4){
    int g = batch[n];
    if (g != cur_g){
      atomicAdd(&sums[cur_g * DOUT + lane], acc);
      acc = 0.f; cur_g = g;
    }
    acc += out2[(size_t)n * DOUT + lane];
  }
  atomicAdd(&sums[cur_g * DOUT + lane], acc);
}

__global__ __launch_bounds__(256) void k_final(const float* __restrict__ sums,
                                               const int* __restrict__ gs,
                                               const float* __restrict__ b2,
                                               float* __restrict__ out){
  int idx = blockIdx.x * 256 + threadIdx.x;
  if (idx >= NG * DOUT) return;
  int g = idx >> 6, f = idx & 63;
  int c = gs[g + 1] - gs[g];
  out[idx] = sums[idx] / (float)(c > 0 ? c : 1) + b2[f];
}

extern "C" void kernel_launch(void* const* d_in, const int* in_sizes, int n_in,
                              void* d_out, int out_size, void* d_ws, size_t ws_size,
                              hipStream_t stream) {
  const float* x   = (const float*)d_in[0];
  const int*   ei  = (const int*)  d_in[1];
  const int*   bat = (const int*)  d_in[2];
  const float* W1  = (const float*)d_in[3];
  const float* as1 = (const float*)d_in[4];
  const float* ad1 = (const float*)d_in[5];
  const float* b1  = (const float*)d_in[6];
  const float* W2  = (const float*)d_in[7];
  const float* as2 = (const float*)d_in[8];
  const float* ad2 = (const float*)d_in[9];
  const float* b2  = (const float*)d_in[10];
  float* out = (float*)d_out;

  char* p = (char*)d_ws;
  auto alloc = [&](size_t bytes){ void* r = p; p += (bytes + 255) & ~(size_t)255; return r; };
  unsigned short* h1b  = (unsigned short*)alloc((size_t)NN * C1 * 2);
  float* a_s1  = (float*)alloc((size_t)NN * H1 * 4);
  float* a_d1  = (float*)alloc((size_t)NN * H1 * 4);
  float* out1  = (float*)alloc((size_t)NN * C1 * 4);
  unsigned short* h2b  = (unsigned short*)alloc((size_t)NN * DOUT * 2);
  float* a_s2  = (float*)alloc(NN * 4);
  float* a_d2  = (float*)alloc(NN * 4);
  float* out2  = (float*)alloc((size_t)NN * DOUT * 4);
  int*   row   = (int*)alloc((NN + 1) * 4);
  int*   cur   = (int*)alloc(NN * 4);
  int*   tmp   = (int*)alloc(NN * 4);
  int*   btot  = (int*)alloc(512 * 4);
  int*   cnt   = (int*)alloc(NN * 4);
  int*   ssrc  = (int*)alloc((size_t)ET * 4);
  float* sums  = (float*)alloc(NG * DOUT * 4);
  int*   gs    = (int*)alloc((NG + 1) * 4);

  hipMemsetAsync(sums, 0, NG * DOUT * 4, stream);
  hipMemsetAsync(gs, 0xFF, (NG + 1) * 4, stream);
  hipMemsetAsync(cnt, 0, NN * 4, stream);

  // node transform 1
  k_gemm1<<<(NN * C1) / 256, 256, 0, stream>>>(x, W1, as1, ad1, h1b, a_s1, a_d1);

  // counting sort by dst (simple hist; XCD-partitioned scatter)
  k_hist    <<<NE / 256, 256, 0, stream>>>(ei, cnt);
  k_scan_blk<<<NB_SCAN, 256, 0, stream>>>(cnt, tmp, btot);
  k_scan_top<<<1, 512, 0, stream>>>(btot);
  k_scan_fin<<<(NN + 256) / 256, 256, 0, stream>>>(cnt, tmp, btot, row, cur);
  k_scatter8<<<SC_SLABS * 8, 256, 0, stream>>>(ei, cur, ssrc);

  // graph boundaries (for pool counts)
  k_bounds<<<(NN + 255) / 256, 256, 0, stream>>>(bat, gs);
  k_fix<<<1, 64, 0, stream>>>(gs);

  // layer 1 aggregate (+bias+ELU)
  k_agg1<<<(NN * 64) / 256, 256, 0, stream>>>(row, ssrc, a_s1, a_d1, h1b, b1, out1);

  // layer 2
  k_gemm2<<<(NN * DOUT) / 256, 256, 0, stream>>>(out1, W2, as2, ad2, h2b, a_s2, a_d2);
  k_agg2 <<<(NN * 64) / 256, 256, 0, stream>>>(row, ssrc, a_s2, a_d2, h2b, out2);

  // pool + finalize
  k_pool <<<256, 256, 0, stream>>>(out2, bat, sums);
  k_final<<<(NG * DOUT + 255) / 256, 256, 0, stream>>>(sums, gs, b2, out);
}